// Round 5
// baseline (213.581 us; speedup 1.0000x reference)
//
#include <hip/hip_runtime.h>

// SlayerNet SNN forward, MI355X.
// pot1 = FIR129(w1@x) [fused, dbuf matmul + streaming FIR] ; s1 = scan [bits] ;
// pot2 = FIR129(w2@s1) [linearity swap] ; s2 = scan -> d_out (fp32).
// Spike scans: speculative block-parallel + exact fixup (state = last 15 spike
// bits; 15-bit mask match => bitwise-exact state).

#define T_LEN   65536
#define NCH     250
#define NO1     25
#define KTAPS   129      // taps d=0..128, eps[d] = srm[128-d]
#define PAD     128
#define SRM_LEN 257
#define REF_LEN 16
#define THETA_F 10.0f
#define LBLK    128      // scan block length (== 4 x 32-bit words)
#define NBK     512      // NBK*LBLK == T_LEN
#define WARM    128      // speculative warm-up steps
#define TS      256      // conv tile size
#define NWORDS  (T_LEN / 32)
#define CU_UNR  10       // channel unroll (250 = 25 * 10 chunks)

// One gen_spikes step. Matches JAX: u = p + buf[0]; s = (u>=theta);
// buf = shift(buf) + s*ref_next  (mul then add, fp32, no contraction).
__device__ __forceinline__ void srm_step(float p, const float (&rn)[15], float (&b)[15],
                                         unsigned &m, float &sf_out) {
  float u = p + b[0];
  unsigned sp = (u >= THETA_F) ? 1u : 0u;
  float sf = sp ? 1.0f : 0.0f;
#pragma unroll
  for (int j = 0; j < 14; ++j) b[j] = __fadd_rn(b[j + 1], __fmul_rn(sf, rn[j]));
  b[14] = __fmul_rn(sf, rn[14]);
  m = (m << 1) | sp;
  sf_out = sf;
}

__global__ void k_fill(float* out, float v) {
  out[blockIdx.x * 256 + threadIdx.x] = v;
}

// load one channel-chunk (20 values) into named register buffers
#define LOADC(dst_a, dst_b, cbase)                                         \
  _Pragma("unroll")                                                        \
  for (int u = 0; u < CU_UNR; ++u) {                                       \
    const float* xr = x + (size_t)((cbase) + u) * T_LEN;                   \
    dst_a[u] = (!GUARD || gA >= 0) ? xr[gA] : 0.0f;                        \
    dst_b[u] = (vB && (!GUARD || gB >= 0)) ? xr[gB] : 0.0f;                \
  }
// consume one chunk: per-acc[o] channel order stays ascending
#define CONSUME(src_a, src_b, cbase)                                       \
  _Pragma("unroll")                                                        \
  for (int o = 0; o < NO1; ++o) {                                          \
    _Pragma("unroll")                                                      \
    for (int u = 0; u < CU_UNR; ++u) {                                     \
      float w = w1[o * NCH + (cbase) + u];                                 \
      acc0[o] = __builtin_fmaf(w, src_a[u], acc0[o]);                      \
      acc1[o] = __builtin_fmaf(w, src_b[u], acc1[o]);                      \
    }                                                                      \
  }

template <bool GUARD>
__device__ __forceinline__ void pot1_accum(const float* __restrict__ x,
                                           const float* __restrict__ w1,
                                           int gA, int gB, bool vB,
                                           float (&acc0)[NO1], float (&acc1)[NO1]) {
  float xaA[CU_UNR], xbA[CU_UNR], xaB[CU_UNR], xbB[CU_UNR];
  LOADC(xaA, xbA, 0)
  for (int g = 0; g < 12; ++g) {  // chunks 0..23 in pairs, prefetch 1 ahead
    LOADC(xaB, xbB, g * 2 * CU_UNR + CU_UNR)
    CONSUME(xaA, xbA, g * 2 * CU_UNR)
    LOADC(xaA, xbA, g * 2 * CU_UNR + 2 * CU_UNR)
    CONSUME(xaB, xbB, g * 2 * CU_UNR + CU_UNR)
  }
  CONSUME(xaA, xbA, 24 * CU_UNR)  // chunk 24
}

// K1 (fused): pot1[o][t] = sum_d eps[d] * (w1 @ x)[o][t-d]
__global__ __launch_bounds__(TS) void k_pot1(const float* __restrict__ x,
                                             const float* __restrict__ w1,
                                             const float* __restrict__ srm,
                                             float* __restrict__ pot1) {
  __shared__ __align__(16) float ys[NO1][TS + PAD];  // 25 x 384
  const int tid = threadIdx.x;
  const int t0 = blockIdx.x * TS;
  const int g0 = t0 - PAD;
  const int gA = g0 + tid;
  const int gB = g0 + TS + tid;
  const bool vB = tid < PAD;
  float acc0[NO1], acc1[NO1];
#pragma unroll
  for (int o = 0; o < NO1; ++o) { acc0[o] = 0.0f; acc1[o] = 0.0f; }
  if (g0 >= 0) pot1_accum<false>(x, w1, gA, gB, vB, acc0, acc1);
  else         pot1_accum<true >(x, w1, gA, gB, vB, acc0, acc1);
#pragma unroll
  for (int o = 0; o < NO1; ++o) {
    ys[o][tid] = acc0[o];
    if (vB) ys[o][TS + tid] = acc1[o];
  }
  __syncthreads();
  // FIR: 4 consecutive outputs/thread; stream float4 from LDS, consume
  // immediately (NO temp array -> no scratch). i descending => per-output
  // tap order d ascending (matches verified accumulation order).
  const int q = tid & 63;
  const int op = tid >> 6;   // 0..3
  const int tloc = q * 4;
  for (int pass = 0; pass < 7; ++pass) {
    int o = pass * 4 + op;   // wave-uniform
    if (o < NO1) {
      float f0 = 0.0f, f1 = 0.0f, f2 = 0.0f, f3 = 0.0f;
#pragma unroll
      for (int i = 32; i >= 0; --i) {
        float4 v = *(const float4*)&ys[o][tloc + 4 * i];
#pragma unroll
        for (int l = 3; l >= 0; --l) {
          float vl = (l == 0) ? v.x : (l == 1) ? v.y : (l == 2) ? v.z : v.w;
          // tap for output k: d = 128 + k - 4i - l ; e = srm[4i + l - k]
#pragma unroll
          for (int k = 0; k < 4; ++k) {
            int d = 128 + k - 4 * i - l;
            if (d >= 0 && d <= 128) {
              float e = srm[4 * i + l - k];  // uniform -> scalar load
              if (k == 0) f0 = __builtin_fmaf(e, vl, f0);
              else if (k == 1) f1 = __builtin_fmaf(e, vl, f1);
              else if (k == 2) f2 = __builtin_fmaf(e, vl, f2);
              else f3 = __builtin_fmaf(e, vl, f3);
            }
          }
        }
      }
      *(float4*)&pot1[(size_t)o * T_LEN + t0 + tloc] = make_float4(f0, f1, f2, f3);
    }
  }
}

// K4: pot2 = FIR129( z ),  z[t] = sum_o w2[o] * s1[o][t]  (bit-packed s1).
__global__ __launch_bounds__(TS) void k_pot2(const unsigned* __restrict__ s1p,
                                             const float* __restrict__ srm,
                                             const float* __restrict__ w2,
                                             float* __restrict__ pot2) {
  __shared__ float zs[TS + PAD];
  const int tid = threadIdx.x;
  const int t0 = blockIdx.x * TS;
  const int g0 = t0 - PAD;
  {
    int g = g0 + tid;
    float z = 0.0f;
    if (g >= 0) {
      int wi = g >> 5, sh = g & 31;
#pragma unroll
      for (int o = 0; o < NO1; ++o) {
        unsigned wv = s1p[o * NWORDS + wi];
        z += ((wv >> sh) & 1u) ? w2[o] : 0.0f;  // w2[o]: uniform scalar load
      }
    }
    zs[tid] = z;
    if (tid < PAD) {
      int g2 = g0 + TS + tid;  // always in [128, T_LEN)
      int wi = g2 >> 5, sh = g2 & 31;
      float z2 = 0.0f;
#pragma unroll
      for (int o = 0; o < NO1; ++o) {
        unsigned wv = s1p[o * NWORDS + wi];
        z2 += ((wv >> sh) & 1u) ? w2[o] : 0.0f;
      }
      zs[TS + tid] = z2;
    }
  }
  __syncthreads();
  float a = 0.0f;
#pragma unroll
  for (int d = 0; d < KTAPS; ++d) {
    float e = srm[PAD - d];
    a = __builtin_fmaf(e, zs[PAD + tid - d], a);
  }
  pot2[t0 + tid] = a;
}

// Speculative scan: one thread per (channel, block). WARM steps from assumed
// zero state, then LBLK emitted steps; records entry mask + exit mask/state.
template <int C, bool PACKED>
__global__ __launch_bounds__(256) void k_scan_spec(const float* __restrict__ pot,
                                                   const float* __restrict__ refk,
                                                   float* __restrict__ s,
                                                   unsigned* __restrict__ sp_,
                                                   unsigned* __restrict__ specin_m,
                                                   unsigned* __restrict__ specout_m,
                                                   float* __restrict__ specout_b) {
  int idx = blockIdx.x * 256 + threadIdx.x;
  if (idx >= C * NBK) return;
  int c = idx / NBK;
  int bb = idx - c * NBK;
  int tsr = bb * LBLK - WARM;
  float rn[15];
#pragma unroll
  for (int j = 0; j < 15; ++j) rn[j] = refk[j + 1];
  float b[15];
#pragma unroll
  for (int j = 0; j < 15; ++j) b[j] = 0.0f;
  unsigned m = 0;
  const float* prow = pot + (size_t)c * T_LEN;
  float* srow = PACKED ? nullptr : (s + (size_t)c * T_LEN);
  unsigned* srowp = PACKED ? (sp_ + (size_t)c * NWORDS) : nullptr;
  for (int k = 0; k < WARM + LBLK; k += 4) {
    if (k == WARM) specin_m[idx] = m & 0x7FFFu;
    int t = tsr + k;
    if (t < 0) continue;
    float4 pv = *(const float4*)(prow + t);
    float s0, s1v, s2, s3;
    srm_step(pv.x, rn, b, m, s0);
    srm_step(pv.y, rn, b, m, s1v);
    srm_step(pv.z, rn, b, m, s2);
    srm_step(pv.w, rn, b, m, s3);
    if (k >= WARM) {
      if (PACKED) {
        if (((t + 3) & 31) == 31) srowp[(t - 28) >> 5] = __brev(m);
      } else {
        *(float4*)(srow + t) = make_float4(s0, s1v, s2, s3);
      }
    }
  }
  specout_m[idx] = m & 0x7FFFu;
#pragma unroll
  for (int j = 0; j < 15; ++j) specout_b[idx * 16 + j] = b[j];
}

// Exact fixup: one WAVE per channel. All 8 mask-groups preloaded (independent
// loads in flight), ballot chain check => 64 blocks/iter fast path; mismatch
// path walks blocks via shuffles with redundant per-lane recompute.
template <int C, bool PACKED>
__global__ __launch_bounds__(64) void k_scan_fix(const float* __restrict__ pot,
                                                 const float* __restrict__ refk,
                                                 float* __restrict__ s,
                                                 unsigned* __restrict__ sp_,
                                                 const unsigned* __restrict__ specin_m,
                                                 const unsigned* __restrict__ specout_m,
                                                 const float* __restrict__ specout_b) {
  const int c = blockIdx.x;
  const int lane = threadIdx.x;
  float rn[15];
#pragma unroll
  for (int j = 0; j < 15; ++j) rn[j] = refk[j + 1];
  float b[15];
#pragma unroll
  for (int j = 0; j < 15; ++j) b[j] = 0.0f;
  unsigned m = 0;
  bool haveB = true;
  const float* prow = pot + (size_t)c * T_LEN;
  float* srow = PACKED ? nullptr : (s + (size_t)c * T_LEN);
  unsigned* srowp = PACKED ? (sp_ + (size_t)c * NWORDS) : nullptr;
  unsigned prev_last = 0;

  unsigned siv[NBK / 64], sov[NBK / 64];
#pragma unroll
  for (int g = 0; g < NBK / 64; ++g) {
    siv[g] = specin_m[c * NBK + g * 64 + lane];
    sov[g] = specout_m[c * NBK + g * 64 + lane];
  }
#pragma unroll
  for (int g = 0; g < NBK / 64; ++g) {
    const unsigned si = siv[g];
    const unsigned so = sov[g];
    unsigned so_prev = __shfl_up(so, 1);
    if (lane == 0) so_prev = prev_last;
    const unsigned long long flags = __ballot(si == so_prev);
    prev_last = __shfl(so, 63);
    const unsigned si0 = __shfl(si, 0);
    if (flags == ~0ull && (m & 0x7FFFu) == si0) {
      m = prev_last;   // whole group chain-consistent => spec is truth
      haveB = false;
      continue;
    }
    for (int r = 0; r < 64; ++r) {
      const unsigned sir = __shfl(si, r);
      const unsigned sor = __shfl(so, r);
      if ((m & 0x7FFFu) == sir) {
        m = sor;
        haveB = false;
      } else {
        const int bbr = g * 64 + r;  // bbr>=1: block 0 entry mask 0 always matches
        if (!haveB) {
          const int pb = (c * NBK + bbr - 1) * 16;
#pragma unroll
          for (int q2 = 0; q2 < 15; ++q2) b[q2] = specout_b[pb + q2];
          haveB = true;
        }
        const int t0 = bbr * LBLK;
        for (int t = t0; t < t0 + LBLK; t += 4) {
          float4 pv = *(const float4*)(prow + t);  // uniform -> broadcast
          float s0, s1v, s2, s3;
          srm_step(pv.x, rn, b, m, s0);
          srm_step(pv.y, rn, b, m, s1v);
          srm_step(pv.z, rn, b, m, s2);
          srm_step(pv.w, rn, b, m, s3);
          if (PACKED) {
            if ((((t + 3) & 31) == 31) && lane == 0) srowp[(t - 28) >> 5] = __brev(m);
          } else {
            if (lane == 0) *(float4*)(srow + t) = make_float4(s0, s1v, s2, s3);
          }
        }
        haveB = true;
      }
    }
  }
}

extern "C" void kernel_launch(void* const* d_in, const int* in_sizes, int n_in,
                              void* d_out, int out_size, void* d_ws, size_t ws_size,
                              hipStream_t stream) {
  const float* x    = (const float*)d_in[0];  // 250*65536
  const float* srm  = (const float*)d_in[1];  // 257
  const float* refk = (const float*)d_in[2];  // 16
  const float* w1   = (const float*)d_in[3];  // 25*250
  const float* w2   = (const float*)d_in[4];  // 25
  float* out = (float*)d_out;

  float bad = 0.0f;
  if (n_in != 5) bad = 3.0f;
  else if (in_sizes[0] != NCH * T_LEN) bad = 4.0f;
  else if (in_sizes[1] != SRM_LEN)     bad = 5.0f;
  else if (in_sizes[2] != REF_LEN)     bad = 6.0f;
  else if (in_sizes[3] != NO1 * NCH)   bad = 7.0f;
  else if (in_sizes[4] != NO1)         bad = 8.0f;
  else if (out_size != T_LEN)          bad = 9.0f;
  if (bad != 0.0f) {
    k_fill<<<T_LEN / 256, 256, 0, stream>>>(out, bad);
    return;
  }

  size_t off = 0;
  auto alloc = [&](size_t bytes) { size_t o = off; off = (off + bytes + 255) & ~(size_t)255; return o; };
  char* ws = (char*)d_ws;
  size_t oP1  = alloc((size_t)NO1 * T_LEN * 4);        // 6.55 MB
  size_t oS1P = alloc((size_t)NO1 * NWORDS * 4);       // 205 KB
  size_t oP2  = alloc((size_t)T_LEN * 4);              // 262 KB
  size_t oSI1 = alloc((size_t)NO1 * NBK * 4);
  size_t oSO1 = alloc((size_t)NO1 * NBK * 4);
  size_t oSB1 = alloc((size_t)NO1 * NBK * 16 * 4);     // 819 KB
  size_t oSI2 = alloc((size_t)NBK * 4);
  size_t oSO2 = alloc((size_t)NBK * 4);
  size_t oSB2 = alloc((size_t)NBK * 16 * 4);
  if (ws_size < off) {
    k_fill<<<T_LEN / 256, 256, 0, stream>>>(out, 2.0f);
    return;
  }

  float*    pot1 = (float*)(ws + oP1);
  unsigned* s1p  = (unsigned*)(ws + oS1P);
  float*    pot2 = (float*)(ws + oP2);
  unsigned* si1  = (unsigned*)(ws + oSI1);
  unsigned* so1  = (unsigned*)(ws + oSO1);
  float*    sb1  = (float*)(ws + oSB1);
  unsigned* si2  = (unsigned*)(ws + oSI2);
  unsigned* so2  = (unsigned*)(ws + oSO2);
  float*    sb2  = (float*)(ws + oSB2);

  k_pot1<<<T_LEN / TS, TS, 0, stream>>>(x, w1, srm, pot1);
  k_scan_spec<NO1, true><<<(NO1 * NBK + 255) / 256, 256, 0, stream>>>(
      pot1, refk, nullptr, s1p, si1, so1, sb1);
  k_scan_fix<NO1, true><<<NO1, 64, 0, stream>>>(pot1, refk, nullptr, s1p, si1, so1, sb1);
  k_pot2<<<T_LEN / TS, TS, 0, stream>>>(s1p, srm, w2, pot2);
  k_scan_spec<1, false><<<(NBK + 255) / 256, 256, 0, stream>>>(
      pot2, refk, out, nullptr, si2, so2, sb2);
  k_scan_fix<1, false><<<1, 64, 0, stream>>>(pot2, refk, out, nullptr, si2, so2, sb2);
}

// Round 6
// 167.865 us; speedup vs baseline: 1.2723x; 1.2723x over previous
//
#include <hip/hip_runtime.h>

// SlayerNet SNN forward, MI355X.
// pot1 = FIR129(w1@x) [fused, c-split halves, 512thr/blk] ; s1 = scan [bits] ;
// pot2 = FIR129(w2@s1) [linearity swap] ; s2 = scan -> d_out (fp32).
// Spike scans: speculative block-parallel + exact fixup (state = last 15 spike
// bits; 15-bit mask match => bitwise-exact state).

#define T_LEN   65536
#define NCH     250
#define NO1     25
#define KTAPS   129      // taps d=0..128, eps[d] = srm[128-d]
#define PAD     128
#define SRM_LEN 257
#define REF_LEN 16
#define THETA_F 10.0f
#define LBLK    128      // scan block length (== 4 x 32-bit words)
#define NBK     512      // NBK*LBLK == T_LEN
#define WARM    128      // speculative warm-up steps
#define TS1     128      // pot1 tile (window = 256)
#define WIN     (TS1 + PAD)
#define TS      256      // pot2 tile size
#define NWORDS  (T_LEN / 32)

// One gen_spikes step. fma(s,rn,b) is bit-exact vs fadd(b,fmul(s,rn)):
// s in {0,1} makes the product exact, so single-rounding = same rounding.
__device__ __forceinline__ void srm_step(float p, const float (&rn)[15], float (&b)[15],
                                         unsigned &m, float &sf_out) {
  float u = p + b[0];
  unsigned sp = (u >= THETA_F) ? 1u : 0u;
  float sf = sp ? 1.0f : 0.0f;
#pragma unroll
  for (int j = 0; j < 14; ++j) b[j] = __builtin_fmaf(sf, rn[j], b[j + 1]);
  b[14] = __fmul_rn(sf, rn[14]);
  m = (m << 1) | sp;
  sf_out = sf;
}

__global__ void k_fill(float* out, float v) {
  out[blockIdx.x * 256 + threadIdx.x] = v;
}

// transpose w1 (25x250) -> w1T (250x25) so per-channel weights are contiguous
__global__ __launch_bounds__(256) void k_prep(const float* __restrict__ w1,
                                              float* __restrict__ w1T) {
  for (int i = threadIdx.x; i < NO1 * NCH; i += 256) {
    int c = i / NO1, o = i - c * NO1;
    w1T[i] = w1[o * NCH + c];
  }
}

// K1 (fused): pot1[o][t] = sum_d eps[d] * (w1 @ x)[o][t-d]
// 512 threads: 2 channel-halves x 256 window positions. grid = 512 tiles.
__global__ __launch_bounds__(512, 4) void k_pot1(const float* __restrict__ x,
                                                 const float* __restrict__ w1T,
                                                 const float* __restrict__ srm,
                                                 float* __restrict__ pot1) {
  __shared__ __align__(16) float ys[2][NO1][WIN];  // 51.2 KB
  const int tid = threadIdx.x;
  const int half = tid >> 8;
  const int pos = tid & 255;
  const int t0 = blockIdx.x * TS1;
  const int g = t0 - PAD + pos;
  float acc[NO1];
#pragma unroll
  for (int o = 0; o < NO1; ++o) acc[o] = 0.0f;
  const int cbase = half * 125;
  if (g >= 0) {
    const float* xp = x + (size_t)cbase * T_LEN + g;
    for (int cb = 0; cb < 125; cb += 5) {
      float xv[5];
#pragma unroll
      for (int u = 0; u < 5; ++u) xv[u] = xp[(size_t)(cb + u) * T_LEN];
#pragma unroll
      for (int u = 0; u < 5; ++u) {
        const float* wr = w1T + (size_t)(cbase + cb + u) * NO1;  // 25 consecutive
#pragma unroll
        for (int o = 0; o < NO1; ++o) acc[o] = __builtin_fmaf(wr[o], xv[u], acc[o]);
      }
    }
  }
#pragma unroll
  for (int o = 0; o < NO1; ++o) ys[half][o][pos] = acc[o];
  __syncthreads();
  {  // fold halves: ys[0] += ys[1]  (c-sum = [0,125) + [125,250))
    float* f0 = &ys[0][0][0];
    const float* f1 = &ys[1][0][0];
    for (int i = tid; i < NO1 * WIN; i += 512) f0[i] = __fadd_rn(f0[i], f1[i]);
  }
  __syncthreads();
  // FIR: quad tasks (o, qt): 25*32 = 800 tasks over 512 threads, 2 passes.
  // i descending => per-output tap order d ascending (proven ordering).
  for (int pass = 0; pass < 2; ++pass) {
    int task = pass * 512 + tid;
    if (task < NO1 * (TS1 / 4)) {
      int o = task >> 5;
      int base = (task & 31) * 4;
      float q0 = 0.0f, q1 = 0.0f, q2 = 0.0f, q3 = 0.0f;
#pragma unroll
      for (int i = 32; i >= 0; --i) {
        float4 v = *(const float4*)&ys[0][o][base + 4 * i];
#pragma unroll
        for (int l = 3; l >= 0; --l) {
          float vl = (l == 0) ? v.x : (l == 1) ? v.y : (l == 2) ? v.z : v.w;
#pragma unroll
          for (int k = 0; k < 4; ++k) {
            int d = 128 + k - 4 * i - l;
            if (d >= 0 && d <= 128) {
              float e = srm[4 * i + l - k];  // uniform -> scalar load
              if (k == 0) q0 = __builtin_fmaf(e, vl, q0);
              else if (k == 1) q1 = __builtin_fmaf(e, vl, q1);
              else if (k == 2) q2 = __builtin_fmaf(e, vl, q2);
              else q3 = __builtin_fmaf(e, vl, q3);
            }
          }
        }
      }
      *(float4*)&pot1[(size_t)o * T_LEN + t0 + base] = make_float4(q0, q1, q2, q3);
    }
  }
}

// K4: pot2 = FIR129( z ),  z[t] = sum_o w2[o] * s1[o][t]  (bit-packed s1).
__global__ __launch_bounds__(TS) void k_pot2(const unsigned* __restrict__ s1p,
                                             const float* __restrict__ srm,
                                             const float* __restrict__ w2,
                                             float* __restrict__ pot2) {
  __shared__ float zs[TS + PAD];
  const int tid = threadIdx.x;
  const int t0 = blockIdx.x * TS;
  const int g0 = t0 - PAD;
  {
    int g = g0 + tid;
    float z = 0.0f;
    if (g >= 0) {
      int wi = g >> 5, sh = g & 31;
#pragma unroll
      for (int o = 0; o < NO1; ++o) {
        unsigned wv = s1p[o * NWORDS + wi];
        z += ((wv >> sh) & 1u) ? w2[o] : 0.0f;
      }
    }
    zs[tid] = z;
    if (tid < PAD) {
      int g2 = g0 + TS + tid;
      int wi = g2 >> 5, sh = g2 & 31;
      float z2 = 0.0f;
#pragma unroll
      for (int o = 0; o < NO1; ++o) {
        unsigned wv = s1p[o * NWORDS + wi];
        z2 += ((wv >> sh) & 1u) ? w2[o] : 0.0f;
      }
      zs[TS + tid] = z2;
    }
  }
  __syncthreads();
  float a = 0.0f;
#pragma unroll
  for (int d = 0; d < KTAPS; ++d) {
    float e = srm[PAD - d];
    a = __builtin_fmaf(e, zs[PAD + tid - d], a);
  }
  pot2[t0 + tid] = a;
}

// Speculative scan: one thread per (channel, block). WARM steps from assumed
// zero state, then LBLK emitted steps; records entry mask + exit mask/state.
template <int C, bool PACKED>
__global__ __launch_bounds__(64) void k_scan_spec(const float* __restrict__ pot,
                                                  const float* __restrict__ refk,
                                                  float* __restrict__ s,
                                                  unsigned* __restrict__ sp_,
                                                  unsigned* __restrict__ specin_m,
                                                  unsigned* __restrict__ specout_m,
                                                  float* __restrict__ specout_b) {
  int idx = blockIdx.x * 64 + threadIdx.x;
  if (idx >= C * NBK) return;
  int c = idx / NBK;
  int bb = idx - c * NBK;
  int tsr = bb * LBLK - WARM;
  float rn[15];
#pragma unroll
  for (int j = 0; j < 15; ++j) rn[j] = refk[j + 1];
  float b[15];
#pragma unroll
  for (int j = 0; j < 15; ++j) b[j] = 0.0f;
  unsigned m = 0;
  const float* prow = pot + (size_t)c * T_LEN;
  float* srow = PACKED ? nullptr : (s + (size_t)c * T_LEN);
  unsigned* srowp = PACKED ? (sp_ + (size_t)c * NWORDS) : nullptr;
  for (int k = 0; k < WARM + LBLK; k += 4) {
    if (k == WARM) specin_m[idx] = m & 0x7FFFu;
    int t = tsr + k;
    if (t < 0) continue;
    float4 pv = *(const float4*)(prow + t);
    float s0, s1v, s2, s3;
    srm_step(pv.x, rn, b, m, s0);
    srm_step(pv.y, rn, b, m, s1v);
    srm_step(pv.z, rn, b, m, s2);
    srm_step(pv.w, rn, b, m, s3);
    if (k >= WARM) {
      if (PACKED) {
        if (((t + 3) & 31) == 31) srowp[(t - 28) >> 5] = __brev(m);
      } else {
        *(float4*)(srow + t) = make_float4(s0, s1v, s2, s3);
      }
    }
  }
  specout_m[idx] = m & 0x7FFFu;
#pragma unroll
  for (int j = 0; j < 15; ++j) specout_b[idx * 16 + j] = b[j];
}

// Exact fixup: one WAVE per channel. All 8 mask-groups preloaded, ballot chain
// check => 64 blocks/iter fast path; mismatch path walks via shuffles.
template <int C, bool PACKED>
__global__ __launch_bounds__(64) void k_scan_fix(const float* __restrict__ pot,
                                                 const float* __restrict__ refk,
                                                 float* __restrict__ s,
                                                 unsigned* __restrict__ sp_,
                                                 const unsigned* __restrict__ specin_m,
                                                 const unsigned* __restrict__ specout_m,
                                                 const float* __restrict__ specout_b) {
  const int c = blockIdx.x;
  const int lane = threadIdx.x;
  float rn[15];
#pragma unroll
  for (int j = 0; j < 15; ++j) rn[j] = refk[j + 1];
  float b[15];
#pragma unroll
  for (int j = 0; j < 15; ++j) b[j] = 0.0f;
  unsigned m = 0;
  bool haveB = true;
  const float* prow = pot + (size_t)c * T_LEN;
  float* srow = PACKED ? nullptr : (s + (size_t)c * T_LEN);
  unsigned* srowp = PACKED ? (sp_ + (size_t)c * NWORDS) : nullptr;
  unsigned prev_last = 0;

  unsigned siv[NBK / 64], sov[NBK / 64];
#pragma unroll
  for (int g = 0; g < NBK / 64; ++g) {
    siv[g] = specin_m[c * NBK + g * 64 + lane];
    sov[g] = specout_m[c * NBK + g * 64 + lane];
  }
#pragma unroll
  for (int g = 0; g < NBK / 64; ++g) {
    const unsigned si = siv[g];
    const unsigned so = sov[g];
    unsigned so_prev = __shfl_up(so, 1);
    if (lane == 0) so_prev = prev_last;
    const unsigned long long flags = __ballot(si == so_prev);
    prev_last = __shfl(so, 63);
    const unsigned si0 = __shfl(si, 0);
    if (flags == ~0ull && (m & 0x7FFFu) == si0) {
      m = prev_last;
      haveB = false;
      continue;
    }
    for (int r = 0; r < 64; ++r) {
      const unsigned sir = __shfl(si, r);
      const unsigned sor = __shfl(so, r);
      if ((m & 0x7FFFu) == sir) {
        m = sor;
        haveB = false;
      } else {
        const int bbr = g * 64 + r;  // bbr>=1: block 0 entry mask 0 always matches
        if (!haveB) {
          const int pb = (c * NBK + bbr - 1) * 16;
#pragma unroll
          for (int q2 = 0; q2 < 15; ++q2) b[q2] = specout_b[pb + q2];
          haveB = true;
        }
        const int t0 = bbr * LBLK;
        for (int t = t0; t < t0 + LBLK; t += 4) {
          float4 pv = *(const float4*)(prow + t);
          float s0, s1v, s2, s3;
          srm_step(pv.x, rn, b, m, s0);
          srm_step(pv.y, rn, b, m, s1v);
          srm_step(pv.z, rn, b, m, s2);
          srm_step(pv.w, rn, b, m, s3);
          if (PACKED) {
            if ((((t + 3) & 31) == 31) && lane == 0) srowp[(t - 28) >> 5] = __brev(m);
          } else {
            if (lane == 0) *(float4*)(srow + t) = make_float4(s0, s1v, s2, s3);
          }
        }
        haveB = true;
      }
    }
  }
}

extern "C" void kernel_launch(void* const* d_in, const int* in_sizes, int n_in,
                              void* d_out, int out_size, void* d_ws, size_t ws_size,
                              hipStream_t stream) {
  const float* x    = (const float*)d_in[0];  // 250*65536
  const float* srm  = (const float*)d_in[1];  // 257
  const float* refk = (const float*)d_in[2];  // 16
  const float* w1   = (const float*)d_in[3];  // 25*250
  const float* w2   = (const float*)d_in[4];  // 25
  float* out = (float*)d_out;

  float bad = 0.0f;
  if (n_in != 5) bad = 3.0f;
  else if (in_sizes[0] != NCH * T_LEN) bad = 4.0f;
  else if (in_sizes[1] != SRM_LEN)     bad = 5.0f;
  else if (in_sizes[2] != REF_LEN)     bad = 6.0f;
  else if (in_sizes[3] != NO1 * NCH)   bad = 7.0f;
  else if (in_sizes[4] != NO1)         bad = 8.0f;
  else if (out_size != T_LEN)          bad = 9.0f;
  if (bad != 0.0f) {
    k_fill<<<T_LEN / 256, 256, 0, stream>>>(out, bad);
    return;
  }

  size_t off = 0;
  auto alloc = [&](size_t bytes) { size_t o = off; off = (off + bytes + 255) & ~(size_t)255; return o; };
  char* ws = (char*)d_ws;
  size_t oP1  = alloc((size_t)NO1 * T_LEN * 4);        // 6.55 MB
  size_t oS1P = alloc((size_t)NO1 * NWORDS * 4);       // 205 KB
  size_t oP2  = alloc((size_t)T_LEN * 4);              // 262 KB
  size_t oW1T = alloc((size_t)NO1 * NCH * 4);          // 25 KB
  size_t oSI1 = alloc((size_t)NO1 * NBK * 4);
  size_t oSO1 = alloc((size_t)NO1 * NBK * 4);
  size_t oSB1 = alloc((size_t)NO1 * NBK * 16 * 4);     // 819 KB
  size_t oSI2 = alloc((size_t)NBK * 4);
  size_t oSO2 = alloc((size_t)NBK * 4);
  size_t oSB2 = alloc((size_t)NBK * 16 * 4);
  if (ws_size < off) {
    k_fill<<<T_LEN / 256, 256, 0, stream>>>(out, 2.0f);
    return;
  }

  float*    pot1 = (float*)(ws + oP1);
  unsigned* s1p  = (unsigned*)(ws + oS1P);
  float*    pot2 = (float*)(ws + oP2);
  float*    w1T  = (float*)(ws + oW1T);
  unsigned* si1  = (unsigned*)(ws + oSI1);
  unsigned* so1  = (unsigned*)(ws + oSO1);
  float*    sb1  = (float*)(ws + oSB1);
  unsigned* si2  = (unsigned*)(ws + oSI2);
  unsigned* so2  = (unsigned*)(ws + oSO2);
  float*    sb2  = (float*)(ws + oSB2);

  k_prep<<<1, 256, 0, stream>>>(w1, w1T);
  k_pot1<<<T_LEN / TS1, 512, 0, stream>>>(x, w1T, srm, pot1);
  k_scan_spec<NO1, true><<<(NO1 * NBK + 63) / 64, 64, 0, stream>>>(
      pot1, refk, nullptr, s1p, si1, so1, sb1);
  k_scan_fix<NO1, true><<<NO1, 64, 0, stream>>>(pot1, refk, nullptr, s1p, si1, so1, sb1);
  k_pot2<<<T_LEN / TS, TS, 0, stream>>>(s1p, srm, w2, pot2);
  k_scan_spec<1, false><<<(NBK + 63) / 64, 64, 0, stream>>>(
      pot2, refk, out, nullptr, si2, so2, sb2);
  k_scan_fix<1, false><<<1, 64, 0, stream>>>(pot2, refk, out, nullptr, si2, so2, sb2);
}

// Round 7
// 161.973 us; speedup vs baseline: 1.3186x; 1.0364x over previous
//
#include <hip/hip_runtime.h>

// SlayerNet SNN forward, MI355X.
// y1 = w1@x [k_mm1, c-quartered] ; pot1 = FIR129(y1) [k_fir1] ; s1 = scan ;
// pot2 = FIR129(w2@s1) [linearity swap] ; s2 = scan -> d_out (fp32).
// Spike scans: speculative block-parallel + exact fixup (state = last 15 spike
// bits; 15-bit mask match => bitwise-exact state).

#define T_LEN   65536
#define NCH     250
#define NO1     25
#define KTAPS   129      // taps d=0..128, eps[d] = srm[128-d]
#define PAD     128
#define SRM_LEN 257
#define REF_LEN 16
#define THETA_F 10.0f
#define LBLK    128      // scan block length (== 4 x 32-bit words)
#define NBK     512      // NBK*LBLK == T_LEN
#define WARM    128      // speculative warm-up steps
#define TS      256      // pot2 tile size
#define FTILE   1024     // fir1 tile
#define NWORDS  (T_LEN / 32)

// One gen_spikes step. fma(s,rn,b) is bit-exact vs fadd(b,fmul(s,rn)):
// s in {0,1} makes the product exact, so single rounding = same rounding.
__device__ __forceinline__ void srm_step(float p, const float (&rn)[15], float (&b)[15],
                                         unsigned &m, float &sf_out) {
  float u = p + b[0];
  unsigned sp = (u >= THETA_F) ? 1u : 0u;
  float sf = sp ? 1.0f : 0.0f;
#pragma unroll
  for (int j = 0; j < 14; ++j) b[j] = __builtin_fmaf(sf, rn[j], b[j + 1]);
  b[14] = __fmul_rn(sf, rn[14]);
  m = (m << 1) | sp;
  sf_out = sf;
}

__global__ void k_fill(float* out, float v) {
  out[blockIdx.x * 256 + threadIdx.x] = v;
}

// transpose w1 (25x250) -> w1T (250x25) so per-channel weights are contiguous
__global__ __launch_bounds__(256) void k_prep(const float* __restrict__ w1,
                                              float* __restrict__ w1T) {
  for (int i = threadIdx.x; i < NO1 * NCH; i += 256) {
    int c = i / NO1, o = i - c * NO1;
    w1T[i] = w1[o * NCH + c];
  }
}

template <int CC>
__device__ __forceinline__ void mm_accum(const float* __restrict__ xp,
                                         const float* __restrict__ wt,
                                         float (&acc)[NO1]) {
#pragma unroll
  for (int cb = 0; cb + 5 <= CC; cb += 5) {
    float xv[5];
#pragma unroll
    for (int u = 0; u < 5; ++u) xv[u] = xp[(size_t)(cb + u) * T_LEN];
#pragma unroll
    for (int u = 0; u < 5; ++u) {
      const float* wr = wt + (cb + u) * NO1;  // uniform -> scalar loads
#pragma unroll
      for (int o = 0; o < NO1; ++o) acc[o] = __builtin_fmaf(wr[o], xv[u], acc[o]);
    }
  }
  constexpr int done = (CC / 5) * 5;
  float xt[CC - done];
#pragma unroll
  for (int u = 0; u < CC - done; ++u) xt[u] = xp[(size_t)(done + u) * T_LEN];
#pragma unroll
  for (int u = 0; u < CC - done; ++u) {
    const float* wr = wt + (done + u) * NO1;
#pragma unroll
    for (int o = 0; o < NO1; ++o) acc[o] = __builtin_fmaf(wr[o], xt[u], acc[o]);
  }
}

// K1: y1[o][t] = sum_c w1[o,c]*x[c][t]. Block = 64 positions x 4 c-quarters.
__global__ __launch_bounds__(256, 6) void k_mm1(const float* __restrict__ x,
                                                const float* __restrict__ w1T,
                                                float* __restrict__ y1) {
  __shared__ float part[4][NO1][64];  // 25.6 KB
  const int tid = threadIdx.x;
  const int lane = tid & 63;
  const int q = tid >> 6;
  const int t = blockIdx.x * 64 + lane;
  const int cstart = q * 62 + (q < 2 ? q : 2);  // 63,63,62,62
  float acc[NO1];
#pragma unroll
  for (int o = 0; o < NO1; ++o) acc[o] = 0.0f;
  const float* xp = x + (size_t)cstart * T_LEN + t;
  const float* wt = w1T + cstart * NO1;
  if (q < 2) mm_accum<63>(xp, wt, acc);
  else       mm_accum<62>(xp, wt, acc);
#pragma unroll
  for (int o = 0; o < NO1; ++o) part[q][o][lane] = acc[o];
  __syncthreads();
  for (int j = tid; j < NO1 * 64; j += 256) {
    int o = j >> 6, l = j & 63;
    float v = __fadd_rn(__fadd_rn(__fadd_rn(part[0][o][l], part[1][o][l]),
                                  part[2][o][l]), part[3][o][l]);
    y1[(size_t)o * T_LEN + blockIdx.x * 64 + l] = v;
  }
}

// K2: pot1[o][t] = sum_d eps[d]*y1[o][t-d]. Grid (T/FTILE, 25).
__global__ __launch_bounds__(256, 8) void k_fir1(const float* __restrict__ y1,
                                                 const float* __restrict__ srm,
                                                 float* __restrict__ pot1) {
  __shared__ __align__(16) float win[FTILE + PAD];
  const int tid = threadIdx.x;
  const int o = blockIdx.y;
  const int t0 = blockIdx.x * FTILE;
  const float* yr = y1 + (size_t)o * T_LEN;
  for (int j = tid; j < FTILE + PAD; j += 256) {
    int g = t0 - PAD + j;
    win[j] = (g >= 0) ? yr[g] : 0.0f;
  }
  __syncthreads();
  const int base = tid * 4;
  float q0 = 0.0f, q1 = 0.0f, q2 = 0.0f, q3 = 0.0f;
  // i descending => per-output tap order d ascending (proven ordering).
#pragma unroll
  for (int i = 32; i >= 0; --i) {
    float4 v = *(const float4*)&win[base + 4 * i];
#pragma unroll
    for (int l = 3; l >= 0; --l) {
      float vl = (l == 0) ? v.x : (l == 1) ? v.y : (l == 2) ? v.z : v.w;
#pragma unroll
      for (int k = 0; k < 4; ++k) {
        int d = 128 + k - 4 * i - l;
        if (d >= 0 && d <= 128) {
          float e = srm[4 * i + l - k];  // uniform -> scalar load
          if (k == 0) q0 = __builtin_fmaf(e, vl, q0);
          else if (k == 1) q1 = __builtin_fmaf(e, vl, q1);
          else if (k == 2) q2 = __builtin_fmaf(e, vl, q2);
          else q3 = __builtin_fmaf(e, vl, q3);
        }
      }
    }
  }
  *(float4*)&pot1[(size_t)o * T_LEN + t0 + base] = make_float4(q0, q1, q2, q3);
}

// K5: pot2 = FIR129( z ),  z[t] = sum_o w2[o] * s1[o][t]  (bit-packed s1).
__global__ __launch_bounds__(TS) void k_pot2(const unsigned* __restrict__ s1p,
                                             const float* __restrict__ srm,
                                             const float* __restrict__ w2,
                                             float* __restrict__ pot2) {
  __shared__ float zs[TS + PAD];
  const int tid = threadIdx.x;
  const int t0 = blockIdx.x * TS;
  const int g0 = t0 - PAD;
  {
    int g = g0 + tid;
    float z = 0.0f;
    if (g >= 0) {
      int wi = g >> 5, sh = g & 31;
#pragma unroll
      for (int o = 0; o < NO1; ++o) {
        unsigned wv = s1p[o * NWORDS + wi];
        z += ((wv >> sh) & 1u) ? w2[o] : 0.0f;
      }
    }
    zs[tid] = z;
    if (tid < PAD) {
      int g2 = g0 + TS + tid;
      int wi = g2 >> 5, sh = g2 & 31;
      float z2 = 0.0f;
#pragma unroll
      for (int o = 0; o < NO1; ++o) {
        unsigned wv = s1p[o * NWORDS + wi];
        z2 += ((wv >> sh) & 1u) ? w2[o] : 0.0f;
      }
      zs[TS + tid] = z2;
    }
  }
  __syncthreads();
  float a = 0.0f;
#pragma unroll
  for (int d = 0; d < KTAPS; ++d) {
    float e = srm[PAD - d];
    a = __builtin_fmaf(e, zs[PAD + tid - d], a);
  }
  pot2[t0 + tid] = a;
}

// Speculative scan: one thread per (channel, block). WARM steps from assumed
// zero state, then LBLK emitted steps; records entry mask + exit mask/state.
template <int C, bool PACKED>
__global__ __launch_bounds__(64) void k_scan_spec(const float* __restrict__ pot,
                                                  const float* __restrict__ refk,
                                                  float* __restrict__ s,
                                                  unsigned* __restrict__ sp_,
                                                  unsigned* __restrict__ specin_m,
                                                  unsigned* __restrict__ specout_m,
                                                  float* __restrict__ specout_b) {
  int idx = blockIdx.x * 64 + threadIdx.x;
  if (idx >= C * NBK) return;
  int c = idx / NBK;
  int bb = idx - c * NBK;
  int tsr = bb * LBLK - WARM;
  float rn[15];
#pragma unroll
  for (int j = 0; j < 15; ++j) rn[j] = refk[j + 1];
  float b[15];
#pragma unroll
  for (int j = 0; j < 15; ++j) b[j] = 0.0f;
  unsigned m = 0;
  const float* prow = pot + (size_t)c * T_LEN;
  float* srow = PACKED ? nullptr : (s + (size_t)c * T_LEN);
  unsigned* srowp = PACKED ? (sp_ + (size_t)c * NWORDS) : nullptr;
  for (int k = 0; k < WARM + LBLK; k += 4) {
    if (k == WARM) specin_m[idx] = m & 0x7FFFu;
    int t = tsr + k;
    if (t < 0) continue;
    float4 pv = *(const float4*)(prow + t);
    float s0, s1v, s2, s3;
    srm_step(pv.x, rn, b, m, s0);
    srm_step(pv.y, rn, b, m, s1v);
    srm_step(pv.z, rn, b, m, s2);
    srm_step(pv.w, rn, b, m, s3);
    if (k >= WARM) {
      if (PACKED) {
        if (((t + 3) & 31) == 31) srowp[(t - 28) >> 5] = __brev(m);
      } else {
        *(float4*)(srow + t) = make_float4(s0, s1v, s2, s3);
      }
    }
  }
  specout_m[idx] = m & 0x7FFFu;
#pragma unroll
  for (int j = 0; j < 15; ++j) specout_b[idx * 16 + j] = b[j];
}

// Exact fixup: one WAVE per channel. All 8 mask-groups preloaded, ballot chain
// check => 64 blocks/iter fast path; mismatch path walks via shuffles.
template <int C, bool PACKED>
__global__ __launch_bounds__(64) void k_scan_fix(const float* __restrict__ pot,
                                                 const float* __restrict__ refk,
                                                 float* __restrict__ s,
                                                 unsigned* __restrict__ sp_,
                                                 const unsigned* __restrict__ specin_m,
                                                 const unsigned* __restrict__ specout_m,
                                                 const float* __restrict__ specout_b) {
  const int c = blockIdx.x;
  const int lane = threadIdx.x;
  float rn[15];
#pragma unroll
  for (int j = 0; j < 15; ++j) rn[j] = refk[j + 1];
  float b[15];
#pragma unroll
  for (int j = 0; j < 15; ++j) b[j] = 0.0f;
  unsigned m = 0;
  bool haveB = true;
  const float* prow = pot + (size_t)c * T_LEN;
  float* srow = PACKED ? nullptr : (s + (size_t)c * T_LEN);
  unsigned* srowp = PACKED ? (sp_ + (size_t)c * NWORDS) : nullptr;
  unsigned prev_last = 0;

  unsigned siv[NBK / 64], sov[NBK / 64];
#pragma unroll
  for (int g = 0; g < NBK / 64; ++g) {
    siv[g] = specin_m[c * NBK + g * 64 + lane];
    sov[g] = specout_m[c * NBK + g * 64 + lane];
  }
#pragma unroll
  for (int g = 0; g < NBK / 64; ++g) {
    const unsigned si = siv[g];
    const unsigned so = sov[g];
    unsigned so_prev = __shfl_up(so, 1);
    if (lane == 0) so_prev = prev_last;
    const unsigned long long flags = __ballot(si == so_prev);
    prev_last = __shfl(so, 63);
    const unsigned si0 = __shfl(si, 0);
    if (flags == ~0ull && (m & 0x7FFFu) == si0) {
      m = prev_last;
      haveB = false;
      continue;
    }
    for (int r = 0; r < 64; ++r) {
      const unsigned sir = __shfl(si, r);
      const unsigned sor = __shfl(so, r);
      if ((m & 0x7FFFu) == sir) {
        m = sor;
        haveB = false;
      } else {
        const int bbr = g * 64 + r;  // bbr>=1: block 0 entry mask 0 always matches
        if (!haveB) {
          const int pb = (c * NBK + bbr - 1) * 16;
#pragma unroll
          for (int q2 = 0; q2 < 15; ++q2) b[q2] = specout_b[pb + q2];
          haveB = true;
        }
        const int t0 = bbr * LBLK;
        for (int t = t0; t < t0 + LBLK; t += 4) {
          float4 pv = *(const float4*)(prow + t);
          float s0, s1v, s2, s3;
          srm_step(pv.x, rn, b, m, s0);
          srm_step(pv.y, rn, b, m, s1v);
          srm_step(pv.z, rn, b, m, s2);
          srm_step(pv.w, rn, b, m, s3);
          if (PACKED) {
            if ((((t + 3) & 31) == 31) && lane == 0) srowp[(t - 28) >> 5] = __brev(m);
          } else {
            if (lane == 0) *(float4*)(srow + t) = make_float4(s0, s1v, s2, s3);
          }
        }
        haveB = true;
      }
    }
  }
}

extern "C" void kernel_launch(void* const* d_in, const int* in_sizes, int n_in,
                              void* d_out, int out_size, void* d_ws, size_t ws_size,
                              hipStream_t stream) {
  const float* x    = (const float*)d_in[0];  // 250*65536
  const float* srm  = (const float*)d_in[1];  // 257
  const float* refk = (const float*)d_in[2];  // 16
  const float* w1   = (const float*)d_in[3];  // 25*250
  const float* w2   = (const float*)d_in[4];  // 25
  float* out = (float*)d_out;

  float bad = 0.0f;
  if (n_in != 5) bad = 3.0f;
  else if (in_sizes[0] != NCH * T_LEN) bad = 4.0f;
  else if (in_sizes[1] != SRM_LEN)     bad = 5.0f;
  else if (in_sizes[2] != REF_LEN)     bad = 6.0f;
  else if (in_sizes[3] != NO1 * NCH)   bad = 7.0f;
  else if (in_sizes[4] != NO1)         bad = 8.0f;
  else if (out_size != T_LEN)          bad = 9.0f;
  if (bad != 0.0f) {
    k_fill<<<T_LEN / 256, 256, 0, stream>>>(out, bad);
    return;
  }

  size_t off = 0;
  auto alloc = [&](size_t bytes) { size_t o = off; off = (off + bytes + 255) & ~(size_t)255; return o; };
  char* ws = (char*)d_ws;
  size_t oY1  = alloc((size_t)NO1 * T_LEN * 4);        // 6.55 MB (dead after k_fir1)
  size_t oP1  = alloc((size_t)NO1 * T_LEN * 4);        // 6.55 MB
  size_t oS1P = alloc((size_t)NO1 * NWORDS * 4);       // 205 KB
  size_t oP2  = alloc((size_t)T_LEN * 4);              // 262 KB
  size_t oW1T = alloc((size_t)NO1 * NCH * 4);          // 25 KB
  if (ws_size < off) {
    k_fill<<<T_LEN / 256, 256, 0, stream>>>(out, 2.0f);
    return;
  }

  float*    y1   = (float*)(ws + oY1);
  float*    pot1 = (float*)(ws + oP1);
  unsigned* s1p  = (unsigned*)(ws + oS1P);
  float*    pot2 = (float*)(ws + oP2);
  float*    w1T  = (float*)(ws + oW1T);
  // spec buffers alias the y1 region (y1 dead once k_fir1 completes; spec
  // kernels launch after k_fir1 in stream order). Offsets 256-aligned.
  char* yb = ws + oY1;
  unsigned* si1 = (unsigned*)(yb);                 // 51200 B
  unsigned* so1 = (unsigned*)(yb + 51200);         // 51200 B
  float*    sb1 = (float*)   (yb + 102400);        // 819200 B
  unsigned* si2 = (unsigned*)(yb + 921600);        // 2048 B
  unsigned* so2 = (unsigned*)(yb + 923648);        // 2048 B
  float*    sb2 = (float*)   (yb + 925696);        // 32768 B

  k_prep<<<1, 256, 0, stream>>>(w1, w1T);
  k_mm1<<<T_LEN / 64, 256, 0, stream>>>(x, w1T, y1);
  k_fir1<<<dim3(T_LEN / FTILE, NO1), 256, 0, stream>>>(y1, srm, pot1);
  k_scan_spec<NO1, true><<<(NO1 * NBK + 63) / 64, 64, 0, stream>>>(
      pot1, refk, nullptr, s1p, si1, so1, sb1);
  k_scan_fix<NO1, true><<<NO1, 64, 0, stream>>>(pot1, refk, nullptr, s1p, si1, so1, sb1);
  k_pot2<<<T_LEN / TS, TS, 0, stream>>>(s1p, srm, w2, pot2);
  k_scan_spec<1, false><<<(NBK + 63) / 64, 64, 0, stream>>>(
      pot2, refk, out, nullptr, si2, so2, sb2);
  k_scan_fix<1, false><<<1, 64, 0, stream>>>(pot2, refk, out, nullptr, si2, so2, sb2);
}

// Round 8
// 99.681 us; speedup vs baseline: 2.1426x; 1.6249x over previous
//
#include <hip/hip_runtime.h>

// SlayerNet SNN forward, MI355X.
// y1t = w1@x [k_mm1, tiled layout, LDS weights] ; pot1 = FIR129(y1t) [k_fir1] ;
// s1 = scan [bits] ; pot2 = FIR129(w2@s1) ; s2 = scan -> d_out (fp32).
// Spike scans: speculative block-parallel + exact fixup (state = last 15 spike
// bits; 15-bit mask match => bitwise-exact state).

#define T_LEN   65536
#define NCH     250
#define NO1     25
#define KTAPS   129      // taps d=0..128, eps[d] = srm[128-d]
#define PAD     128
#define SRM_LEN 257
#define REF_LEN 16
#define THETA_F 10.0f
#define LBLK    128      // scan block length (== 4 x 32-bit words)
#define NBK     512      // NBK*LBLK == T_LEN
#define WARM    128      // speculative warm-up steps
#define TS      256      // pot2 tile size
#define TT      256      // mm1 time-tile (y1t tile width)
#define FTILE   1024     // fir1 tile
#define NWORDS  (T_LEN / 32)

// One gen_spikes step. fma(s,rn,b) is bit-exact vs fadd(b,fmul(s,rn)):
// s in {0,1} makes the product exact, so single rounding = same rounding.
__device__ __forceinline__ void srm_step(float p, const float (&rn)[15], float (&b)[15],
                                         unsigned &m, float &sf_out) {
  float u = p + b[0];
  unsigned sp = (u >= THETA_F) ? 1u : 0u;
  float sf = sp ? 1.0f : 0.0f;
#pragma unroll
  for (int j = 0; j < 14; ++j) b[j] = __builtin_fmaf(sf, rn[j], b[j + 1]);
  b[14] = __fmul_rn(sf, rn[14]);
  m = (m << 1) | sp;
  sf_out = sf;
}

__global__ void k_fill(float* out, float v) {
  out[blockIdx.x * 256 + threadIdx.x] = v;
}

// transpose w1 (25x250) -> w1T (250x25) so per-channel weights are contiguous
__global__ __launch_bounds__(256) void k_prep(const float* __restrict__ w1,
                                              float* __restrict__ w1T) {
  for (int i = threadIdx.x; i < NO1 * NCH; i += 256) {
    int c = i / NO1, o = i - c * NO1;
    w1T[i] = w1[o * NCH + c];
  }
}

// K1: y1t[tile][o][p] = sum_c w1[o,c]*x[c][tile*TT+p].
// Block = TT positions (lane*4 float4) x 4 c-quarters (63,63,62,62).
// Weights from LDS (uniform broadcast); fold via LDS in 2 o-chunks;
// output tiled => each block writes one contiguous 25.6 KB region (float4).
__global__ __launch_bounds__(256) void k_mm1(const float* __restrict__ x,
                                             const float* __restrict__ w1T,
                                             float* __restrict__ y1t) {
  __shared__ __align__(16) float wlds[NCH * NO1];    // 25000 B
  __shared__ __align__(16) float part[4][13][TT];    // 53248 B
  const int tid = threadIdx.x;
  const int lane = tid & 63;
  const int w = tid >> 6;
  const int t0 = blockIdx.x * TT;
  // stage weights -> LDS (coalesced float4, one tail pair)
  for (int j = tid * 4; j < NCH * NO1; j += 1024) {
    if (j + 4 <= NCH * NO1) *(float4*)&wlds[j] = *(const float4*)&w1T[j];
    else { for (int u = j; u < NCH * NO1; ++u) wlds[u] = w1T[u]; }
  }
  __syncthreads();
  const int cs = w * 62 + (w < 2 ? w : 2);   // 0,63,126,188
  const int cn = (w < 2) ? 63 : 62;
  const float* xp = x + (size_t)cs * T_LEN + t0 + lane * 4;
  float acc[NO1][4];
#pragma unroll
  for (int o = 0; o < NO1; ++o) { acc[o][0] = 0.f; acc[o][1] = 0.f; acc[o][2] = 0.f; acc[o][3] = 0.f; }
  float4 xb0 = *(const float4*)xp;
  float4 xb1 = *(const float4*)(xp + T_LEN);
  for (int ci = 0; ci < cn; ++ci) {
    float4 xv = xb0;
    xb0 = xb1;
    xb1 = (ci + 2 < cn) ? *(const float4*)(xp + (size_t)(ci + 2) * T_LEN)
                        : make_float4(0.f, 0.f, 0.f, 0.f);
    const float* wr = &wlds[(cs + ci) * NO1];  // 25 consecutive, lane-uniform
#pragma unroll
    for (int o = 0; o < NO1; ++o) {
      float wv = wr[o];
      acc[o][0] = __builtin_fmaf(wv, xv.x, acc[o][0]);
      acc[o][1] = __builtin_fmaf(wv, xv.y, acc[o][1]);
      acc[o][2] = __builtin_fmaf(wv, xv.z, acc[o][2]);
      acc[o][3] = __builtin_fmaf(wv, xv.w, acc[o][3]);
    }
  }
  // fold in 2 o-chunks (13, 12); order (p0+p1)+p2)+p3 as before
  float* yb = y1t + (size_t)blockIdx.x * (NO1 * TT);
#pragma unroll
  for (int r = 0; r < 2; ++r) {
    const int ob = r * 13;
    const int oc = r ? 12 : 13;
#pragma unroll
    for (int o = 0; o < 13; ++o) {
      if (o < oc)
        *(float4*)&part[w][o][lane * 4] =
            make_float4(acc[ob + o][0], acc[ob + o][1], acc[ob + o][2], acc[ob + o][3]);
    }
    __syncthreads();
    for (int j = tid; j < oc * (TT / 4); j += 256) {
      int o = j >> 6;
      int p4 = (j & 63) * 4;
      float4 a = *(const float4*)&part[0][o][p4];
      float4 b = *(const float4*)&part[1][o][p4];
      float4 c = *(const float4*)&part[2][o][p4];
      float4 d = *(const float4*)&part[3][o][p4];
      float4 rr;
      rr.x = __fadd_rn(__fadd_rn(__fadd_rn(a.x, b.x), c.x), d.x);
      rr.y = __fadd_rn(__fadd_rn(__fadd_rn(a.y, b.y), c.y), d.y);
      rr.z = __fadd_rn(__fadd_rn(__fadd_rn(a.z, b.z), c.z), d.z);
      rr.w = __fadd_rn(__fadd_rn(__fadd_rn(a.w, b.w), c.w), d.w);
      *(float4*)&yb[(ob + o) * TT + p4] = rr;
    }
    __syncthreads();
  }
}

// K2: pot1[o][t] = sum_d eps[d]*y1[o][t-d]; y1 in tiled layout [tile][o][TT].
__global__ __launch_bounds__(256, 8) void k_fir1(const float* __restrict__ y1t,
                                                 const float* __restrict__ srm,
                                                 float* __restrict__ pot1) {
  __shared__ __align__(16) float win[FTILE + PAD];
  const int tid = threadIdx.x;
  const int o = blockIdx.y;
  const int t0 = blockIdx.x * FTILE;
  for (int j = tid; j < FTILE + PAD; j += 256) {
    int g = t0 - PAD + j;
    win[j] = (g >= 0) ? y1t[(size_t)(g >> 8) * (NO1 * TT) + o * TT + (g & 255)] : 0.0f;
  }
  __syncthreads();
  const int base = tid * 4;
  float q0 = 0.0f, q1 = 0.0f, q2 = 0.0f, q3 = 0.0f;
  // i descending => per-output tap order d ascending (proven ordering).
#pragma unroll
  for (int i = 32; i >= 0; --i) {
    float4 v = *(const float4*)&win[base + 4 * i];
#pragma unroll
    for (int l = 3; l >= 0; --l) {
      float vl = (l == 0) ? v.x : (l == 1) ? v.y : (l == 2) ? v.z : v.w;
#pragma unroll
      for (int k = 0; k < 4; ++k) {
        int d = 128 + k - 4 * i - l;
        if (d >= 0 && d <= 128) {
          float e = srm[4 * i + l - k];  // uniform -> scalar load
          if (k == 0) q0 = __builtin_fmaf(e, vl, q0);
          else if (k == 1) q1 = __builtin_fmaf(e, vl, q1);
          else if (k == 2) q2 = __builtin_fmaf(e, vl, q2);
          else q3 = __builtin_fmaf(e, vl, q3);
        }
      }
    }
  }
  *(float4*)&pot1[(size_t)o * T_LEN + t0 + base] = make_float4(q0, q1, q2, q3);
}

// K5: pot2 = FIR129( z ),  z[t] = sum_o w2[o] * s1[o][t]  (bit-packed s1).
__global__ __launch_bounds__(TS) void k_pot2(const unsigned* __restrict__ s1p,
                                             const float* __restrict__ srm,
                                             const float* __restrict__ w2,
                                             float* __restrict__ pot2) {
  __shared__ float zs[TS + PAD];
  const int tid = threadIdx.x;
  const int t0 = blockIdx.x * TS;
  const int g0 = t0 - PAD;
  {
    int g = g0 + tid;
    float z = 0.0f;
    if (g >= 0) {
      int wi = g >> 5, sh = g & 31;
#pragma unroll
      for (int o = 0; o < NO1; ++o) {
        unsigned wv = s1p[o * NWORDS + wi];
        z += ((wv >> sh) & 1u) ? w2[o] : 0.0f;
      }
    }
    zs[tid] = z;
    if (tid < PAD) {
      int g2 = g0 + TS + tid;
      int wi = g2 >> 5, sh = g2 & 31;
      float z2 = 0.0f;
#pragma unroll
      for (int o = 0; o < NO1; ++o) {
        unsigned wv = s1p[o * NWORDS + wi];
        z2 += ((wv >> sh) & 1u) ? w2[o] : 0.0f;
      }
      zs[TS + tid] = z2;
    }
  }
  __syncthreads();
  float a = 0.0f;
#pragma unroll
  for (int d = 0; d < KTAPS; ++d) {
    float e = srm[PAD - d];
    a = __builtin_fmaf(e, zs[PAD + tid - d], a);
  }
  pot2[t0 + tid] = a;
}

// Speculative scan: one thread per (channel, block). WARM steps from assumed
// zero state, then LBLK emitted steps; records entry mask + exit mask/state.
template <int C, bool PACKED>
__global__ __launch_bounds__(64) void k_scan_spec(const float* __restrict__ pot,
                                                  const float* __restrict__ refk,
                                                  float* __restrict__ s,
                                                  unsigned* __restrict__ sp_,
                                                  unsigned* __restrict__ specin_m,
                                                  unsigned* __restrict__ specout_m,
                                                  float* __restrict__ specout_b) {
  int idx = blockIdx.x * 64 + threadIdx.x;
  if (idx >= C * NBK) return;
  int c = idx / NBK;
  int bb = idx - c * NBK;
  int tsr = bb * LBLK - WARM;
  float rn[15];
#pragma unroll
  for (int j = 0; j < 15; ++j) rn[j] = refk[j + 1];
  float b[15];
#pragma unroll
  for (int j = 0; j < 15; ++j) b[j] = 0.0f;
  unsigned m = 0;
  const float* prow = pot + (size_t)c * T_LEN;
  float* srow = PACKED ? nullptr : (s + (size_t)c * T_LEN);
  unsigned* srowp = PACKED ? (sp_ + (size_t)c * NWORDS) : nullptr;
  for (int k = 0; k < WARM + LBLK; k += 4) {
    if (k == WARM) specin_m[idx] = m & 0x7FFFu;
    int t = tsr + k;
    if (t < 0) continue;
    float4 pv = *(const float4*)(prow + t);
    float s0, s1v, s2, s3;
    srm_step(pv.x, rn, b, m, s0);
    srm_step(pv.y, rn, b, m, s1v);
    srm_step(pv.z, rn, b, m, s2);
    srm_step(pv.w, rn, b, m, s3);
    if (k >= WARM) {
      if (PACKED) {
        if (((t + 3) & 31) == 31) srowp[(t - 28) >> 5] = __brev(m);
      } else {
        *(float4*)(srow + t) = make_float4(s0, s1v, s2, s3);
      }
    }
  }
  specout_m[idx] = m & 0x7FFFu;
#pragma unroll
  for (int j = 0; j < 15; ++j) specout_b[idx * 16 + j] = b[j];
}

// Exact fixup: one WAVE per channel. All 8 mask-groups preloaded, ballot chain
// check => 64 blocks/iter fast path; mismatch path walks via shuffles.
template <int C, bool PACKED>
__global__ __launch_bounds__(64) void k_scan_fix(const float* __restrict__ pot,
                                                 const float* __restrict__ refk,
                                                 float* __restrict__ s,
                                                 unsigned* __restrict__ sp_,
                                                 const unsigned* __restrict__ specin_m,
                                                 const unsigned* __restrict__ specout_m,
                                                 const float* __restrict__ specout_b) {
  const int c = blockIdx.x;
  const int lane = threadIdx.x;
  float rn[15];
#pragma unroll
  for (int j = 0; j < 15; ++j) rn[j] = refk[j + 1];
  float b[15];
#pragma unroll
  for (int j = 0; j < 15; ++j) b[j] = 0.0f;
  unsigned m = 0;
  bool haveB = true;
  const float* prow = pot + (size_t)c * T_LEN;
  float* srow = PACKED ? nullptr : (s + (size_t)c * T_LEN);
  unsigned* srowp = PACKED ? (sp_ + (size_t)c * NWORDS) : nullptr;
  unsigned prev_last = 0;

  unsigned siv[NBK / 64], sov[NBK / 64];
#pragma unroll
  for (int g = 0; g < NBK / 64; ++g) {
    siv[g] = specin_m[c * NBK + g * 64 + lane];
    sov[g] = specout_m[c * NBK + g * 64 + lane];
  }
#pragma unroll
  for (int g = 0; g < NBK / 64; ++g) {
    const unsigned si = siv[g];
    const unsigned so = sov[g];
    unsigned so_prev = __shfl_up(so, 1);
    if (lane == 0) so_prev = prev_last;
    const unsigned long long flags = __ballot(si == so_prev);
    prev_last = __shfl(so, 63);
    const unsigned si0 = __shfl(si, 0);
    if (flags == ~0ull && (m & 0x7FFFu) == si0) {
      m = prev_last;
      haveB = false;
      continue;
    }
    for (int r = 0; r < 64; ++r) {
      const unsigned sir = __shfl(si, r);
      const unsigned sor = __shfl(so, r);
      if ((m & 0x7FFFu) == sir) {
        m = sor;
        haveB = false;
      } else {
        const int bbr = g * 64 + r;  // bbr>=1: block 0 entry mask 0 always matches
        if (!haveB) {
          const int pb = (c * NBK + bbr - 1) * 16;
#pragma unroll
          for (int q2 = 0; q2 < 15; ++q2) b[q2] = specout_b[pb + q2];
          haveB = true;
        }
        const int t0 = bbr * LBLK;
        for (int t = t0; t < t0 + LBLK; t += 4) {
          float4 pv = *(const float4*)(prow + t);
          float s0, s1v, s2, s3;
          srm_step(pv.x, rn, b, m, s0);
          srm_step(pv.y, rn, b, m, s1v);
          srm_step(pv.z, rn, b, m, s2);
          srm_step(pv.w, rn, b, m, s3);
          if (PACKED) {
            if ((((t + 3) & 31) == 31) && lane == 0) srowp[(t - 28) >> 5] = __brev(m);
          } else {
            if (lane == 0) *(float4*)(srow + t) = make_float4(s0, s1v, s2, s3);
          }
        }
        haveB = true;
      }
    }
  }
}

extern "C" void kernel_launch(void* const* d_in, const int* in_sizes, int n_in,
                              void* d_out, int out_size, void* d_ws, size_t ws_size,
                              hipStream_t stream) {
  const float* x    = (const float*)d_in[0];  // 250*65536
  const float* srm  = (const float*)d_in[1];  // 257
  const float* refk = (const float*)d_in[2];  // 16
  const float* w1   = (const float*)d_in[3];  // 25*250
  const float* w2   = (const float*)d_in[4];  // 25
  float* out = (float*)d_out;

  float bad = 0.0f;
  if (n_in != 5) bad = 3.0f;
  else if (in_sizes[0] != NCH * T_LEN) bad = 4.0f;
  else if (in_sizes[1] != SRM_LEN)     bad = 5.0f;
  else if (in_sizes[2] != REF_LEN)     bad = 6.0f;
  else if (in_sizes[3] != NO1 * NCH)   bad = 7.0f;
  else if (in_sizes[4] != NO1)         bad = 8.0f;
  else if (out_size != T_LEN)          bad = 9.0f;
  if (bad != 0.0f) {
    k_fill<<<T_LEN / 256, 256, 0, stream>>>(out, bad);
    return;
  }

  size_t off = 0;
  auto alloc = [&](size_t bytes) { size_t o = off; off = (off + bytes + 255) & ~(size_t)255; return o; };
  char* ws = (char*)d_ws;
  size_t oY1  = alloc((size_t)NO1 * T_LEN * 4);        // 6.55 MB (dead after k_fir1)
  size_t oP1  = alloc((size_t)NO1 * T_LEN * 4);        // 6.55 MB
  size_t oS1P = alloc((size_t)NO1 * NWORDS * 4);       // 205 KB
  size_t oP2  = alloc((size_t)T_LEN * 4);              // 262 KB
  size_t oW1T = alloc((size_t)NO1 * NCH * 4);          // 25 KB
  if (ws_size < off) {
    k_fill<<<T_LEN / 256, 256, 0, stream>>>(out, 2.0f);
    return;
  }

  float*    y1t  = (float*)(ws + oY1);
  float*    pot1 = (float*)(ws + oP1);
  unsigned* s1p  = (unsigned*)(ws + oS1P);
  float*    pot2 = (float*)(ws + oP2);
  float*    w1T  = (float*)(ws + oW1T);
  // spec buffers alias the y1t region (dead once k_fir1 completes; spec
  // kernels launch after k_fir1 in stream order). Offsets 256-aligned.
  char* yb = ws + oY1;
  unsigned* si1 = (unsigned*)(yb);                 // 51200 B
  unsigned* so1 = (unsigned*)(yb + 51200);         // 51200 B
  float*    sb1 = (float*)   (yb + 102400);        // 819200 B
  unsigned* si2 = (unsigned*)(yb + 921600);        // 2048 B
  unsigned* so2 = (unsigned*)(yb + 923648);        // 2048 B
  float*    sb2 = (float*)   (yb + 925696);        // 32768 B

  k_prep<<<1, 256, 0, stream>>>(w1, w1T);
  k_mm1<<<T_LEN / TT, 256, 0, stream>>>(x, w1T, y1t);
  k_fir1<<<dim3(T_LEN / FTILE, NO1), 256, 0, stream>>>(y1t, srm, pot1);
  k_scan_spec<NO1, true><<<(NO1 * NBK + 63) / 64, 64, 0, stream>>>(
      pot1, refk, nullptr, s1p, si1, so1, sb1);
  k_scan_fix<NO1, true><<<NO1, 64, 0, stream>>>(pot1, refk, nullptr, s1p, si1, so1, sb1);
  k_pot2<<<T_LEN / TS, TS, 0, stream>>>(s1p, srm, w2, pot2);
  k_scan_spec<1, false><<<(NBK + 63) / 64, 64, 0, stream>>>(
      pot2, refk, out, nullptr, si2, so2, sb2);
  k_scan_fix<1, false><<<1, 64, 0, stream>>>(pot2, refk, out, nullptr, si2, so2, sb2);
}

// Round 9
// 95.106 us; speedup vs baseline: 2.2457x; 1.0481x over previous
//
#include <hip/hip_runtime.h>

// SlayerNet SNN forward, MI355X.
// y1t = w1@x [k_mm1: 16 wave-uniform c-groups, scalar-pipe weights] ;
// pot1 = FIR129(y1t) [k_fir1] ; s1 = scan [bits] ;
// pot2 = FIR129(w2@s1) [linearity swap] ; s2 = scan -> d_out (fp32).
// Spike scans: speculative block-parallel + exact fixup (state = last 15 spike
// bits; 15-bit mask match => bitwise-exact state).

#define T_LEN   65536
#define NCH     250
#define NO1     25
#define KTAPS   129      // taps d=0..128, eps[d] = srm[128-d]
#define PAD     128
#define SRM_LEN 257
#define REF_LEN 16
#define THETA_F 10.0f
#define LBLK    128      // scan block length (== 4 x 32-bit words)
#define NBK     512      // NBK*LBLK == T_LEN
#define WARM    128      // speculative warm-up steps
#define TS      256      // pot2 tile size
#define TT      256      // mm1 time-tile (y1t tile width)
#define FTILE   1024     // fir1 tile
#define NWORDS  (T_LEN / 32)
#define NGRP    16       // mm1 channel groups (wave-uniform)

// One gen_spikes step. fma(s,rn,b) is bit-exact vs fadd(b,fmul(s,rn)):
// s in {0,1} makes the product exact, so single rounding = same rounding.
__device__ __forceinline__ void srm_step(float p, const float (&rn)[15], float (&b)[15],
                                         unsigned &m, float &sf_out) {
  float u = p + b[0];
  unsigned sp = (u >= THETA_F) ? 1u : 0u;
  float sf = sp ? 1.0f : 0.0f;
#pragma unroll
  for (int j = 0; j < 14; ++j) b[j] = __builtin_fmaf(sf, rn[j], b[j + 1]);
  b[14] = __fmul_rn(sf, rn[14]);
  m = (m << 1) | sp;
  sf_out = sf;
}

__global__ void k_fill(float* out, float v) {
  out[blockIdx.x * 256 + threadIdx.x] = v;
}

// transpose w1 (25x250) -> w1T (250x25) so per-channel weights are contiguous
__global__ __launch_bounds__(256) void k_prep(const float* __restrict__ w1,
                                              float* __restrict__ w1T) {
  for (int i = threadIdx.x; i < NO1 * NCH; i += 256) {
    int c = i / NO1, o = i - c * NO1;
    w1T[i] = w1[o * NCH + c];
  }
}

// K1: y1t[tile][o][p] = sum_c w1[o,c]*x[c][tile*TT+p].
// 1024 threads = 16 waves; wave g owns a contiguous channel group
// (10 groups of 16, 6 of 15); each lane holds a float4 of positions.
// Weights read via wave-uniform (scalar) loads. Fold 16 partials via LDS
// in 5 o-chunks, fixed left-to-right order. Output tiled [tile][o][TT].
__global__ __launch_bounds__(1024, 4) void k_mm1(const float* __restrict__ x,
                                                 const float* __restrict__ w1T,
                                                 float* __restrict__ y1t) {
  __shared__ __align__(16) float part[NGRP][5][TT];  // 80 KB
  const int tid = threadIdx.x;
  const int lane = tid & 63;
  const int wv = __builtin_amdgcn_readfirstlane(tid >> 6);  // wave id, SGPR
  const int t0 = blockIdx.x * TT;
  const int cs = wv * 15 + (wv < 10 ? wv : 10);   // group start
  const int cn = (wv < 10) ? 16 : 15;             // group size
  float acc[NO1][4];
#pragma unroll
  for (int o = 0; o < NO1; ++o) {
    acc[o][0] = 0.f; acc[o][1] = 0.f; acc[o][2] = 0.f; acc[o][3] = 0.f;
  }
  const float* xp = x + (size_t)cs * T_LEN + t0 + lane * 4;
  const float* wt = w1T + cs * NO1;               // SGPR base
  float4 xb0 = *(const float4*)xp;
  float4 xb1 = *(const float4*)(xp + T_LEN);
  for (int ci = 0; ci < cn; ++ci) {
    float4 xv = xb0;
    xb0 = xb1;
    xb1 = (ci + 2 < cn) ? *(const float4*)(xp + (size_t)(ci + 2) * T_LEN)
                        : make_float4(0.f, 0.f, 0.f, 0.f);
    const float* wr = wt + ci * NO1;              // uniform -> s_load batch
#pragma unroll
    for (int o = 0; o < NO1; ++o) {
      float wvv = wr[o];
      acc[o][0] = __builtin_fmaf(wvv, xv.x, acc[o][0]);
      acc[o][1] = __builtin_fmaf(wvv, xv.y, acc[o][1]);
      acc[o][2] = __builtin_fmaf(wvv, xv.z, acc[o][2]);
      acc[o][3] = __builtin_fmaf(wvv, xv.w, acc[o][3]);
    }
  }
  // fold in 5 rounds of 5 outputs each
  float* yb = y1t + (size_t)blockIdx.x * (NO1 * TT);
#pragma unroll
  for (int r = 0; r < 5; ++r) {
#pragma unroll
    for (int oo = 0; oo < 5; ++oo) {
      int o = r * 5 + oo;
      *(float4*)&part[wv][oo][lane * 4] =
          make_float4(acc[o][0], acc[o][1], acc[o][2], acc[o][3]);
    }
    __syncthreads();
    if (tid < 5 * (TT / 4)) {
      int oo = tid >> 6;
      int p4 = (tid & 63) * 4;
      float4 s = *(const float4*)&part[0][oo][p4];
#pragma unroll
      for (int g = 1; g < NGRP; ++g) {
        float4 p = *(const float4*)&part[g][oo][p4];
        s.x = __fadd_rn(s.x, p.x);
        s.y = __fadd_rn(s.y, p.y);
        s.z = __fadd_rn(s.z, p.z);
        s.w = __fadd_rn(s.w, p.w);
      }
      *(float4*)&yb[(r * 5 + oo) * TT + p4] = s;
    }
    __syncthreads();
  }
}

// K2: pot1[o][t] = sum_d eps[d]*y1[o][t-d]; y1 in tiled layout [tile][o][TT].
__global__ __launch_bounds__(256, 8) void k_fir1(const float* __restrict__ y1t,
                                                 const float* __restrict__ srm,
                                                 float* __restrict__ pot1) {
  __shared__ __align__(16) float win[FTILE + PAD];
  const int tid = threadIdx.x;
  const int o = blockIdx.y;
  const int t0 = blockIdx.x * FTILE;
  for (int j = tid; j < FTILE + PAD; j += 256) {
    int g = t0 - PAD + j;
    win[j] = (g >= 0) ? y1t[(size_t)(g >> 8) * (NO1 * TT) + o * TT + (g & 255)] : 0.0f;
  }
  __syncthreads();
  const int base = tid * 4;
  float q0 = 0.0f, q1 = 0.0f, q2 = 0.0f, q3 = 0.0f;
  // i descending => per-output tap order d ascending (proven ordering).
#pragma unroll
  for (int i = 32; i >= 0; --i) {
    float4 v = *(const float4*)&win[base + 4 * i];
#pragma unroll
    for (int l = 3; l >= 0; --l) {
      float vl = (l == 0) ? v.x : (l == 1) ? v.y : (l == 2) ? v.z : v.w;
#pragma unroll
      for (int k = 0; k < 4; ++k) {
        int d = 128 + k - 4 * i - l;
        if (d >= 0 && d <= 128) {
          float e = srm[4 * i + l - k];  // uniform -> scalar load
          if (k == 0) q0 = __builtin_fmaf(e, vl, q0);
          else if (k == 1) q1 = __builtin_fmaf(e, vl, q1);
          else if (k == 2) q2 = __builtin_fmaf(e, vl, q2);
          else q3 = __builtin_fmaf(e, vl, q3);
        }
      }
    }
  }
  *(float4*)&pot1[(size_t)o * T_LEN + t0 + base] = make_float4(q0, q1, q2, q3);
}

// K5: pot2 = FIR129( z ),  z[t] = sum_o w2[o] * s1[o][t]  (bit-packed s1).
__global__ __launch_bounds__(TS) void k_pot2(const unsigned* __restrict__ s1p,
                                             const float* __restrict__ srm,
                                             const float* __restrict__ w2,
                                             float* __restrict__ pot2) {
  __shared__ float zs[TS + PAD];
  const int tid = threadIdx.x;
  const int t0 = blockIdx.x * TS;
  const int g0 = t0 - PAD;
  {
    int g = g0 + tid;
    float z = 0.0f;
    if (g >= 0) {
      int wi = g >> 5, sh = g & 31;
#pragma unroll
      for (int o = 0; o < NO1; ++o) {
        unsigned wvv = s1p[o * NWORDS + wi];
        z += ((wvv >> sh) & 1u) ? w2[o] : 0.0f;
      }
    }
    zs[tid] = z;
    if (tid < PAD) {
      int g2 = g0 + TS + tid;
      int wi = g2 >> 5, sh = g2 & 31;
      float z2 = 0.0f;
#pragma unroll
      for (int o = 0; o < NO1; ++o) {
        unsigned wvv = s1p[o * NWORDS + wi];
        z2 += ((wvv >> sh) & 1u) ? w2[o] : 0.0f;
      }
      zs[TS + tid] = z2;
    }
  }
  __syncthreads();
  float a = 0.0f;
#pragma unroll
  for (int d = 0; d < KTAPS; ++d) {
    float e = srm[PAD - d];
    a = __builtin_fmaf(e, zs[PAD + tid - d], a);
  }
  pot2[t0 + tid] = a;
}

// Speculative scan: one thread per (channel, block). WARM steps from assumed
// zero state, then LBLK emitted steps; records entry mask + exit mask/state.
template <int C, bool PACKED>
__global__ __launch_bounds__(64) void k_scan_spec(const float* __restrict__ pot,
                                                  const float* __restrict__ refk,
                                                  float* __restrict__ s,
                                                  unsigned* __restrict__ sp_,
                                                  unsigned* __restrict__ specin_m,
                                                  unsigned* __restrict__ specout_m,
                                                  float* __restrict__ specout_b) {
  int idx = blockIdx.x * 64 + threadIdx.x;
  if (idx >= C * NBK) return;
  int c = idx / NBK;
  int bb = idx - c * NBK;
  int tsr = bb * LBLK - WARM;
  float rn[15];
#pragma unroll
  for (int j = 0; j < 15; ++j) rn[j] = refk[j + 1];
  float b[15];
#pragma unroll
  for (int j = 0; j < 15; ++j) b[j] = 0.0f;
  unsigned m = 0;
  const float* prow = pot + (size_t)c * T_LEN;
  float* srow = PACKED ? nullptr : (s + (size_t)c * T_LEN);
  unsigned* srowp = PACKED ? (sp_ + (size_t)c * NWORDS) : nullptr;
  for (int k = 0; k < WARM + LBLK; k += 4) {
    if (k == WARM) specin_m[idx] = m & 0x7FFFu;
    int t = tsr + k;
    if (t < 0) continue;
    float4 pv = *(const float4*)(prow + t);
    float s0, s1v, s2, s3;
    srm_step(pv.x, rn, b, m, s0);
    srm_step(pv.y, rn, b, m, s1v);
    srm_step(pv.z, rn, b, m, s2);
    srm_step(pv.w, rn, b, m, s3);
    if (k >= WARM) {
      if (PACKED) {
        if (((t + 3) & 31) == 31) srowp[(t - 28) >> 5] = __brev(m);
      } else {
        *(float4*)(srow + t) = make_float4(s0, s1v, s2, s3);
      }
    }
  }
  specout_m[idx] = m & 0x7FFFu;
#pragma unroll
  for (int j = 0; j < 15; ++j) specout_b[idx * 16 + j] = b[j];
}

// Exact fixup: one WAVE per channel. All 8 mask-groups preloaded, ballot chain
// check => 64 blocks/iter fast path; mismatch path walks via shuffles.
template <int C, bool PACKED>
__global__ __launch_bounds__(64) void k_scan_fix(const float* __restrict__ pot,
                                                 const float* __restrict__ refk,
                                                 float* __restrict__ s,
                                                 unsigned* __restrict__ sp_,
                                                 const unsigned* __restrict__ specin_m,
                                                 const unsigned* __restrict__ specout_m,
                                                 const float* __restrict__ specout_b) {
  const int c = blockIdx.x;
  const int lane = threadIdx.x;
  float rn[15];
#pragma unroll
  for (int j = 0; j < 15; ++j) rn[j] = refk[j + 1];
  float b[15];
#pragma unroll
  for (int j = 0; j < 15; ++j) b[j] = 0.0f;
  unsigned m = 0;
  bool haveB = true;
  const float* prow = pot + (size_t)c * T_LEN;
  float* srow = PACKED ? nullptr : (s + (size_t)c * T_LEN);
  unsigned* srowp = PACKED ? (sp_ + (size_t)c * NWORDS) : nullptr;
  unsigned prev_last = 0;

  unsigned siv[NBK / 64], sov[NBK / 64];
#pragma unroll
  for (int g = 0; g < NBK / 64; ++g) {
    siv[g] = specin_m[c * NBK + g * 64 + lane];
    sov[g] = specout_m[c * NBK + g * 64 + lane];
  }
#pragma unroll
  for (int g = 0; g < NBK / 64; ++g) {
    const unsigned si = siv[g];
    const unsigned so = sov[g];
    unsigned so_prev = __shfl_up(so, 1);
    if (lane == 0) so_prev = prev_last;
    const unsigned long long flags = __ballot(si == so_prev);
    prev_last = __shfl(so, 63);
    const unsigned si0 = __shfl(si, 0);
    if (flags == ~0ull && (m & 0x7FFFu) == si0) {
      m = prev_last;
      haveB = false;
      continue;
    }
    for (int r = 0; r < 64; ++r) {
      const unsigned sir = __shfl(si, r);
      const unsigned sor = __shfl(so, r);
      if ((m & 0x7FFFu) == sir) {
        m = sor;
        haveB = false;
      } else {
        const int bbr = g * 64 + r;  // bbr>=1: block 0 entry mask 0 always matches
        if (!haveB) {
          const int pb = (c * NBK + bbr - 1) * 16;
#pragma unroll
          for (int q2 = 0; q2 < 15; ++q2) b[q2] = specout_b[pb + q2];
          haveB = true;
        }
        const int t0 = bbr * LBLK;
        for (int t = t0; t < t0 + LBLK; t += 4) {
          float4 pv = *(const float4*)(prow + t);
          float s0, s1v, s2, s3;
          srm_step(pv.x, rn, b, m, s0);
          srm_step(pv.y, rn, b, m, s1v);
          srm_step(pv.z, rn, b, m, s2);
          srm_step(pv.w, rn, b, m, s3);
          if (PACKED) {
            if ((((t + 3) & 31) == 31) && lane == 0) srowp[(t - 28) >> 5] = __brev(m);
          } else {
            if (lane == 0) *(float4*)(srow + t) = make_float4(s0, s1v, s2, s3);
          }
        }
        haveB = true;
      }
    }
  }
}

extern "C" void kernel_launch(void* const* d_in, const int* in_sizes, int n_in,
                              void* d_out, int out_size, void* d_ws, size_t ws_size,
                              hipStream_t stream) {
  const float* x    = (const float*)d_in[0];  // 250*65536
  const float* srm  = (const float*)d_in[1];  // 257
  const float* refk = (const float*)d_in[2];  // 16
  const float* w1   = (const float*)d_in[3];  // 25*250
  const float* w2   = (const float*)d_in[4];  // 25
  float* out = (float*)d_out;

  float bad = 0.0f;
  if (n_in != 5) bad = 3.0f;
  else if (in_sizes[0] != NCH * T_LEN) bad = 4.0f;
  else if (in_sizes[1] != SRM_LEN)     bad = 5.0f;
  else if (in_sizes[2] != REF_LEN)     bad = 6.0f;
  else if (in_sizes[3] != NO1 * NCH)   bad = 7.0f;
  else if (in_sizes[4] != NO1)         bad = 8.0f;
  else if (out_size != T_LEN)          bad = 9.0f;
  if (bad != 0.0f) {
    k_fill<<<T_LEN / 256, 256, 0, stream>>>(out, bad);
    return;
  }

  size_t off = 0;
  auto alloc = [&](size_t bytes) { size_t o = off; off = (off + bytes + 255) & ~(size_t)255; return o; };
  char* ws = (char*)d_ws;
  size_t oY1  = alloc((size_t)NO1 * T_LEN * 4);        // 6.55 MB (dead after k_fir1)
  size_t oP1  = alloc((size_t)NO1 * T_LEN * 4);        // 6.55 MB
  size_t oS1P = alloc((size_t)NO1 * NWORDS * 4);       // 205 KB
  size_t oP2  = alloc((size_t)T_LEN * 4);              // 262 KB
  size_t oW1T = alloc((size_t)NO1 * NCH * 4);          // 25 KB
  if (ws_size < off) {
    k_fill<<<T_LEN / 256, 256, 0, stream>>>(out, 2.0f);
    return;
  }

  float*    y1t  = (float*)(ws + oY1);
  float*    pot1 = (float*)(ws + oP1);
  unsigned* s1p  = (unsigned*)(ws + oS1P);
  float*    pot2 = (float*)(ws + oP2);
  float*    w1T  = (float*)(ws + oW1T);
  // spec buffers alias the y1t region (dead once k_fir1 completes; spec
  // kernels launch after k_fir1 in stream order). Offsets 256-aligned.
  char* yb = ws + oY1;
  unsigned* si1 = (unsigned*)(yb);                 // 51200 B
  unsigned* so1 = (unsigned*)(yb + 51200);         // 51200 B
  float*    sb1 = (float*)   (yb + 102400);        // 819200 B
  unsigned* si2 = (unsigned*)(yb + 921600);        // 2048 B
  unsigned* so2 = (unsigned*)(yb + 923648);        // 2048 B
  float*    sb2 = (float*)   (yb + 925696);        // 32768 B

  k_prep<<<1, 256, 0, stream>>>(w1, w1T);
  k_mm1<<<T_LEN / TT, 1024, 0, stream>>>(x, w1T, y1t);
  k_fir1<<<dim3(T_LEN / FTILE, NO1), 256, 0, stream>>>(y1t, srm, pot1);
  k_scan_spec<NO1, true><<<(NO1 * NBK + 63) / 64, 64, 0, stream>>>(
      pot1, refk, nullptr, s1p, si1, so1, sb1);
  k_scan_fix<NO1, true><<<NO1, 64, 0, stream>>>(pot1, refk, nullptr, s1p, si1, so1, sb1);
  k_pot2<<<T_LEN / TS, TS, 0, stream>>>(s1p, srm, w2, pot2);
  k_scan_spec<1, false><<<(NBK + 63) / 64, 64, 0, stream>>>(
      pot2, refk, out, nullptr, si2, so2, sb2);
  k_scan_fix<1, false><<<1, 64, 0, stream>>>(pot2, refk, out, nullptr, si2, so2, sb2);
}